// Round 4
// baseline (289.498 us; speedup 1.0000x reference)
//
#include <hip/hip_runtime.h>
#include <hip/hip_bf16.h>

// Problem constants (fixed by reference)
#define T_TOTAL 786432
#define N_IN 50
#define K_FEAT 400
#define C_OUT 10
#define NSEG 32768                  // T/24 pooled segments

// ---- workspace layout ----
// [0,      51200)  : w1f  — W1 MFMA B-frags, bf16: frag fi=(t*2+s)*64+lane, 8 shorts each
// [51200,  83200)  : w2t  — W2 transposed floats for fallback epilogue
// [83200,  96512)  : w2f  — W2 MFMA B-frags, bf16: fi=kt*64+lane (13 ktiles, zero-padded)
// [98304,  ~27.4M) : pooled — bf16 [32768 segs][416 feats] (stride 416, raw sums, /24 in phase2)
#define W1F_TASKS (25 * 2 * 64)        // 3200
#define W2T_OFF_BYTES 51200
#define W2T_FLOATS (25 * 320)          // 8000 (fallback uses 320-thread mapping)
#define W2F_OFF_BYTES 83200
#define W2F_TASKS (13 * 64)            // 832
#define PREP_TASKS (W1F_TASKS + W2T_FLOATS + W2F_TASKS)
#define POOLED_OFF_BYTES 98304
#define POOLED_STRIDE 416
#define WS_NEEDED (POOLED_OFF_BYTES + (size_t)NSEG * POOLED_STRIDE * 2)

typedef __bf16 bfx8 __attribute__((ext_vector_type(8)));
typedef short  s16x8 __attribute__((ext_vector_type(8)));
typedef float  f32x4 __attribute__((ext_vector_type(4)));

static __device__ __forceinline__ short f2bf(float f) {
    union { float f; unsigned u; } v; v.f = f;
    unsigned r = v.u + 0x7fffu + ((v.u >> 16) & 1u);
    return (short)(r >> 16);
}

// ================= prep: build fragment-ordered weight blobs =================
__global__ void prep_kernel(const float* __restrict__ W1,
                            const float* __restrict__ W2,
                            short* __restrict__ w1f, float* __restrict__ w2t,
                            short* __restrict__ w2f)
{
    const int gid = blockIdx.x * blockDim.x + threadIdx.x;
    if (gid < W1F_TASKS) {
        const int lane = gid & 63;
        const int s    = (gid >> 6) & 1;
        const int tile = gid >> 7;          // 0..24
        const int m16  = lane & 15;
        const int quad = lane >> 4;
        const float* row = W1 + (tile * 16 + m16) * N_IN;
        s16x8 v;
        #pragma unroll
        for (int j = 0; j < 8; ++j) {
            const int n = s * 32 + quad * 8 + j;
            v[j] = (n < N_IN) ? f2bf(row[n]) : (short)0;
        }
        *(s16x8*)&w1f[gid * 8] = v;
    } else if (gid < W1F_TASKS + W2T_FLOATS) {
        const int i   = gid - W1F_TASKS;    // i = j*320 + tid
        const int j   = i / 320;
        const int tid = i - j * 320;
        const int o    = tid >> 4;
        const int part = tid & 15;
        const int seg  = (o >= 10) ? 1 : 0;
        const int cls  = o - seg * 10;
        w2t[i] = W2[cls * K_FEAT + part * 25 + j];
    } else if (gid < PREP_TASKS) {
        // w2f: B-frag for GEMM2. B[k=feat][n=class]: lane holds
        // B[kt*32+quad*8+j][m16] = W2[class=m16][feat], zero outside bounds.
        const int i    = gid - W1F_TASKS - W2T_FLOATS;   // kt*64 + lane
        const int lane = i & 63;
        const int kt   = i >> 6;            // 0..12
        const int m16  = lane & 15;
        const int quad = lane >> 4;
        s16x8 v;
        #pragma unroll
        for (int j = 0; j < 8; ++j) {
            const int feat = kt * 32 + quad * 8 + j;
            v[j] = (m16 < C_OUT && feat < K_FEAT) ? f2bf(W2[m16 * K_FEAT + feat])
                                                  : (short)0;
        }
        *(s16x8*)&w2f[i * 8] = v;
    }
}

// ================= phase 1: GEMM1 + relu + pool (no LDS, no barriers) =======
// wave = 4 chunks (2 groups x 2 chunks); chunk = 48 rows = 2 segments.
// 1024 blocks x 256 thr = 4096 waves x 4 chunks = 16384 chunks.
__global__ __launch_bounds__(256, 3) void phase1_kernel(
    const float* __restrict__ x, const short* __restrict__ w1f,
    short* __restrict__ pooled)
{
    const int tid  = threadIdx.x;
    const int wave = tid >> 6;
    const int lane = tid & 63;
    const int m16  = lane & 15;
    const int quad = lane >> 4;
    const int wgid = blockIdx.x * 4 + wave;          // 0..4095
    const s16x8* wf = (const s16x8*)w1f;

    for (int g = 0; g < 2; ++g) {
        const int group = wgid * 2 + g;              // 0..8191 (2 chunks each)
        const float* xg = x + (size_t)group * (2 * 48 * N_IN);

        // ---- A fragments: 2 chunks x 3 tiles, fp32 global -> bf16 regs ----
        s16x8 A[6][2];
        #pragma unroll
        for (int ct = 0; ct < 6; ++ct) {             // ct = chunk*3 + rtile
            const float* rp = xg + (ct * 16 + m16) * N_IN;
            float v0[8], v1[8];
            #pragma unroll
            for (int h = 0; h < 4; ++h) {            // kstep0: cols quad*8..+7
                const float2 u = *(const float2*)(rp + quad * 8 + 2 * h);
                v0[2 * h] = u.x; v0[2 * h + 1] = u.y;
            }
            if (quad < 2) {                          // kstep1 cols 32..47
                #pragma unroll
                for (int h = 0; h < 4; ++h) {
                    const float2 u = *(const float2*)(rp + 32 + quad * 8 + 2 * h);
                    v1[2 * h] = u.x; v1[2 * h + 1] = u.y;
                }
            } else if (quad == 2) {                  // cols 48,49 then pad
                const float2 u = *(const float2*)(rp + 48);
                v1[0] = u.x; v1[1] = u.y;
                #pragma unroll
                for (int j = 2; j < 8; ++j) v1[j] = 0.f;
            } else {
                #pragma unroll
                for (int j = 0; j < 8; ++j) v1[j] = 0.f;
            }
            s16x8 f0, f1;
            #pragma unroll
            for (int j = 0; j < 8; ++j) { f0[j] = f2bf(v0[j]); f1[j] = f2bf(v1[j]); }
            A[ct][0] = f0; A[ct][1] = f1;
        }

        // ---- t-loop over 25 k-tiles, B double-buffered from L2 blob ----
        s16x8 b0 = wf[lane];          // t=0, s=0
        s16x8 b1 = wf[64 + lane];     // t=0, s=1
        const int seg0 = group * 4;   // 4 segments per group
        for (int t = 0; t < 25; ++t) {
            const int tn = (t < 24) ? t + 1 : 24;
            const s16x8 nb0 = wf[(tn * 2) * 64 + lane];
            const s16x8 nb1 = wf[(tn * 2 + 1) * 64 + lane];
            #pragma unroll
            for (int h = 0; h < 2; ++h) {            // chunk within group
                float c0 = 0.f, c1 = 0.f;
                #pragma unroll
                for (int r = 0; r < 3; ++r) {
                    f32x4 acc = {0.f, 0.f, 0.f, 0.f};
                    acc = __builtin_amdgcn_mfma_f32_16x16x32_bf16(
                            __builtin_bit_cast(bfx8, A[h * 3 + r][0]),
                            __builtin_bit_cast(bfx8, b0), acc, 0, 0, 0);
                    acc = __builtin_amdgcn_mfma_f32_16x16x32_bf16(
                            __builtin_bit_cast(bfx8, A[h * 3 + r][1]),
                            __builtin_bit_cast(bfx8, b1), acc, 0, 0, 0);
                    const float s = fmaxf(acc[0], 0.f) + fmaxf(acc[1], 0.f)
                                  + fmaxf(acc[2], 0.f) + fmaxf(acc[3], 0.f);
                    // lane's 4 rows = group gg=r*4+quad; gg<6 -> seg even
                    if (r * 4 + quad < 6) c0 += s; else c1 += s;
                }
                c0 += __shfl_xor(c0, 16); c0 += __shfl_xor(c0, 32);
                c1 += __shfl_xor(c1, 16); c1 += __shfl_xor(c1, 32);
                if (quad < 2) {
                    const int seg = seg0 + 2 * h + quad;
                    const float cv = (quad == 0) ? c0 : c1;
                    pooled[(size_t)seg * POOLED_STRIDE + t * 16 + m16] = f2bf(cv);
                }
            }
            b0 = nb0; b1 = nb1;
        }
    }
}

// ================= phase 2: pooled[32768x400] @ W2^T via MFMA ===============
// 512 blocks x 256 thr = 2048 waves x 16 segments.
__global__ __launch_bounds__(256) void phase2_kernel(
    const short* __restrict__ pooled, const short* __restrict__ w2f,
    float* __restrict__ out)
{
    const int tid  = threadIdx.x;
    const int lane = tid & 63;
    const int m16  = lane & 15;
    const int quad = lane >> 4;
    const int segbase = (blockIdx.x * 4 + (tid >> 6)) * 16;
    const s16x8* wf = (const s16x8*)w2f;
    const short* arow = pooled + (size_t)(segbase + m16) * POOLED_STRIDE;

    f32x4 acc = {0.f, 0.f, 0.f, 0.f};
    s16x8 zero = {0, 0, 0, 0, 0, 0, 0, 0};
    #pragma unroll
    for (int kt = 0; kt < 13; ++kt) {
        const s16x8 b = wf[kt * 64 + lane];
        // A[m=seg][k=feat]; feats 400..415 are poisoned pad -> mask kt12 q>=2
        const s16x8 a = (kt == 12 && quad >= 2)
                            ? zero
                            : *(const s16x8*)(arow + kt * 32 + quad * 8);
        acc = __builtin_amdgcn_mfma_f32_16x16x32_bf16(
                __builtin_bit_cast(bfx8, a), __builtin_bit_cast(bfx8, b),
                acc, 0, 0, 0);
    }
    // D: row(seg offset)=quad*4+reg, col(class)=m16
    if (m16 < C_OUT) {
        #pragma unroll
        for (int rg = 0; rg < 4; ++rg)
            out[(size_t)(segbase + quad * 4 + rg) * C_OUT + m16] =
                acc[rg] * (1.0f / 24.0f);
    }
}

// ================= fallback (round-3 fused kernel, verbatim) ================
#define FB_CPB 4
#define FB_NTHREADS 320
#define FB_XS_STRIDE 72
#define FB_XS_ROWS (FB_CPB * 48)

__global__ __launch_bounds__(FB_NTHREADS) void classifier_fb(
    const float* __restrict__ x, const short* __restrict__ w1f,
    const float* __restrict__ w2t, float* __restrict__ out)
{
    __shared__ short xs[FB_XS_ROWS * FB_XS_STRIDE];
    __shared__ float pooled[2 * K_FEAT];

    const int tid  = threadIdx.x;
    const int wave = tid >> 6;
    const int lane = tid & 63;
    const int m16  = lane & 15;
    const int quad = lane >> 4;

    {
        const float* xb = x + (size_t)blockIdx.x * (FB_XS_ROWS * N_IN);
        #pragma unroll
        for (int it = 0; it < (FB_XS_ROWS * 25) / FB_NTHREADS; ++it) {
            const int i = tid + it * FB_NTHREADS;
            const int r = i / 25;
            const int c2 = i - r * 25;
            const float2 v = *(const float2*)(xb + 2 * i);
            const int packed = (unsigned short)f2bf(v.x) |
                               ((unsigned)(unsigned short)f2bf(v.y) << 16);
            *(int*)&xs[r * FB_XS_STRIDE + 2 * c2] = packed;
        }
        for (int i = tid; i < FB_XS_ROWS * 7; i += FB_NTHREADS) {
            const int r = i / 7;
            const int c = 50 + 2 * (i - r * 7);
            *(int*)&xs[r * FB_XS_STRIDE + c] = 0;
        }
    }

    s16x8 bfrag[5][2];
    {
        const s16x8* wf = (const s16x8*)w1f;
        #pragma unroll
        for (int t = 0; t < 5; ++t)
            #pragma unroll
            for (int s = 0; s < 2; ++s)
                bfrag[t][s] = wf[((wave * 5 + t) * 2 + s) * 64 + lane];
    }

    const int o    = tid >> 4;
    const int part = tid & 15;
    const int segO = (o >= 10) ? 1 : 0;
    const int cls  = o - segO * 10;
    float w2r[25];
    #pragma unroll
    for (int j = 0; j < 25; ++j) w2r[j] = w2t[j * FB_NTHREADS + tid];

    __syncthreads();

    for (int ciq = 0; ciq < FB_CPB; ++ciq) {
        s16x8 a[3][2];
        #pragma unroll
        for (int r = 0; r < 3; ++r) {
            const short* arow =
                &xs[(ciq * 48 + r * 16 + m16) * FB_XS_STRIDE + quad * 8];
            a[r][0] = *(const s16x8*)(arow);
            a[r][1] = *(const s16x8*)(arow + 32);
        }
        #pragma unroll
        for (int t = 0; t < 5; ++t) {
            float c0 = 0.f, c1 = 0.f;
            #pragma unroll
            for (int r = 0; r < 3; ++r) {
                f32x4 acc = {0.f, 0.f, 0.f, 0.f};
                acc = __builtin_amdgcn_mfma_f32_16x16x32_bf16(
                        __builtin_bit_cast(bfx8, a[r][0]),
                        __builtin_bit_cast(bfx8, bfrag[t][0]), acc, 0, 0, 0);
                acc = __builtin_amdgcn_mfma_f32_16x16x32_bf16(
                        __builtin_bit_cast(bfx8, a[r][1]),
                        __builtin_bit_cast(bfx8, bfrag[t][1]), acc, 0, 0, 0);
                const float s = fmaxf(acc[0], 0.f) + fmaxf(acc[1], 0.f)
                              + fmaxf(acc[2], 0.f) + fmaxf(acc[3], 0.f);
                if (r * 4 + quad < 6) c0 += s; else c1 += s;
            }
            c0 += __shfl_xor(c0, 16); c0 += __shfl_xor(c0, 32);
            c1 += __shfl_xor(c1, 16); c1 += __shfl_xor(c1, 32);
            if (quad == 0) {
                const int feat = (wave * 5 + t) * 16 + m16;
                pooled[feat] = c0;
                pooled[K_FEAT + feat] = c1;
            }
        }
        __syncthreads();

        float sum = 0.f;
        const float* pv = &pooled[segO * K_FEAT + part * 25];
        #pragma unroll
        for (int j = 0; j < 25; ++j) sum += pv[j] * w2r[j];
        sum += __shfl_down(sum, 8, 16);
        sum += __shfl_down(sum, 4, 16);
        sum += __shfl_down(sum, 2, 16);
        sum += __shfl_down(sum, 1, 16);
        if (part == 0) {
            const int chunk = blockIdx.x * FB_CPB + ciq;
            out[(chunk * 2 + segO) * C_OUT + cls] = sum * (1.0f / 24.0f);
        }
        __syncthreads();
    }
}

// ============================== launch ======================================
extern "C" void kernel_launch(void* const* d_in, const int* in_sizes, int n_in,
                              void* d_out, int out_size, void* d_ws, size_t ws_size,
                              hipStream_t stream) {
    const float* x  = (const float*)d_in[0];
    const float* W1 = (const float*)d_in[1];
    const float* W2 = (const float*)d_in[2];
    float* out = (float*)d_out;

    short* w1f = (short*)d_ws;
    float* w2t = (float*)((char*)d_ws + W2T_OFF_BYTES);
    short* w2f = (short*)((char*)d_ws + W2F_OFF_BYTES);
    short* pooled = (short*)((char*)d_ws + POOLED_OFF_BYTES);

    prep_kernel<<<(PREP_TASKS + 255) / 256, 256, 0, stream>>>(W1, W2, w1f, w2t, w2f);

    if (ws_size >= WS_NEEDED) {
        phase1_kernel<<<1024, 256, 0, stream>>>(x, w1f, pooled);
        phase2_kernel<<<512, 256, 0, stream>>>(pooled, w2f, out);
    } else {
        classifier_fb<<<4096, FB_NTHREADS, 0, stream>>>(x, w1f, w2t, out);
    }
}

// Round 5
// 262.766 us; speedup vs baseline: 1.1017x; 1.1017x over previous
//
#include <hip/hip_runtime.h>
#include <hip/hip_bf16.h>

// Problem constants (fixed by reference)
#define T_TOTAL 786432
#define N_IN 50
#define K_FEAT 400
#define C_OUT 10
#define NSEG 32768                  // T/24 pooled segments

// ---- workspace layout ----
// [0,      51200)  : w1f   — W1 16x16 MFMA B-frags (fallback kernel)
// [51200,  83200)  : w2t   — W2 transposed floats (fallback epilogue)
// [83200,  96512)  : w2f   — W2 16x16 MFMA B-frags for phase2
// [98304,  151552) : w1f32 — W1 32x32 MFMA B-frags: frag fi=(ft*4+kt)*64+lane, 8 shorts
// [163840, ~27.4M) : pooled — bf16 [32768 segs][416 feats] (raw sums, /24 in phase2)
#define W1F_TASKS (25 * 2 * 64)        // 3200
#define W2T_OFF_BYTES 51200
#define W2T_FLOATS (25 * 320)          // 8000
#define W2F_OFF_BYTES 83200
#define W2F_TASKS (13 * 64)            // 832
#define W1F32_OFF_BYTES 98304
#define W1F32_TASKS (13 * 4 * 64)      // 3328
#define PREP_TASKS (W1F_TASKS + W2T_FLOATS + W2F_TASKS + W1F32_TASKS)
#define POOLED_OFF_BYTES 163840
#define POOLED_STRIDE 416
#define WS_NEEDED (POOLED_OFF_BYTES + (size_t)NSEG * POOLED_STRIDE * 2)

typedef __bf16 bfx8 __attribute__((ext_vector_type(8)));
typedef short  s16x8 __attribute__((ext_vector_type(8)));
typedef float  f32x4 __attribute__((ext_vector_type(4)));
typedef float  f32x16 __attribute__((ext_vector_type(16)));

static __device__ __forceinline__ short f2bf(float f) {
    union { float f; unsigned u; } v; v.f = f;
    unsigned r = v.u + 0x7fffu + ((v.u >> 16) & 1u);
    return (short)(r >> 16);
}

// ================= prep: build fragment-ordered weight blobs =================
__global__ void prep_kernel(const float* __restrict__ W1,
                            const float* __restrict__ W2,
                            short* __restrict__ w1f, float* __restrict__ w2t,
                            short* __restrict__ w2f, short* __restrict__ w1f32)
{
    const int gid = blockIdx.x * blockDim.x + threadIdx.x;
    if (gid < W1F_TASKS) {
        const int lane = gid & 63;
        const int s    = (gid >> 6) & 1;
        const int tile = gid >> 7;          // 0..24
        const int m16  = lane & 15;
        const int quad = lane >> 4;
        const float* row = W1 + (tile * 16 + m16) * N_IN;
        s16x8 v;
        #pragma unroll
        for (int j = 0; j < 8; ++j) {
            const int n = s * 32 + quad * 8 + j;
            v[j] = (n < N_IN) ? f2bf(row[n]) : (short)0;
        }
        *(s16x8*)&w1f[gid * 8] = v;
    } else if (gid < W1F_TASKS + W2T_FLOATS) {
        const int i   = gid - W1F_TASKS;    // i = j*320 + tid
        const int j   = i / 320;
        const int tid = i - j * 320;
        const int o    = tid >> 4;
        const int part = tid & 15;
        const int seg  = (o >= 10) ? 1 : 0;
        const int cls  = o - seg * 10;
        w2t[i] = W2[cls * K_FEAT + part * 25 + j];
    } else if (gid < W1F_TASKS + W2T_FLOATS + W2F_TASKS) {
        // w2f: B-frag for phase2 (16x16x32). lane holds
        // B[kt*32+quad*8+j][m16] = W2[class=m16][feat], zero outside bounds.
        const int i    = gid - W1F_TASKS - W2T_FLOATS;   // kt*64 + lane
        const int lane = i & 63;
        const int kt   = i >> 6;            // 0..12
        const int m16  = lane & 15;
        const int quad = lane >> 4;
        s16x8 v;
        #pragma unroll
        for (int j = 0; j < 8; ++j) {
            const int feat = kt * 32 + quad * 8 + j;
            v[j] = (m16 < C_OUT && feat < K_FEAT) ? f2bf(W2[m16 * K_FEAT + feat])
                                                  : (short)0;
        }
        *(s16x8*)&w2f[i * 8] = v;
    } else if (gid < PREP_TASKS) {
        // w1f32: B-frag for 32x32x16 GEMM1. B[k][n]: lane l holds
        // B[k=(l>>5)*8+j][n=l&31] = W1[feat=ft*32+(l&31)][col=kt*16+(l>>5)*8+j]
        const int i    = gid - W1F_TASKS - W2T_FLOATS - W2F_TASKS; // (ft*4+kt)*64+lane
        const int lane = i & 63;
        const int fi   = i >> 6;            // 0..51
        const int ft   = fi >> 2;           // 0..12
        const int kt   = fi & 3;            // 0..3
        const int feat = ft * 32 + (lane & 31);
        const int cbase = kt * 16 + (lane >> 5) * 8;
        s16x8 v;
        #pragma unroll
        for (int j = 0; j < 8; ++j) {
            const int col = cbase + j;
            v[j] = (feat < K_FEAT && col < N_IN) ? f2bf(W1[feat * N_IN + col])
                                                 : (short)0;
        }
        *(s16x8*)&w1f32[i * 8] = v;
    }
}

// ======= phase 1: GEMM1(32x32x16) + relu + pool, no LDS / no barriers =======
// wave = one 96-row chunk = 4 pooling segments. 2048 blocks x 4 waves = 8192.
__global__ __launch_bounds__(256, 4) void phase1_kernel(
    const float* __restrict__ x, const short* __restrict__ w1f32,
    short* __restrict__ pooled)
{
    const int tid  = threadIdx.x;
    const int lane = tid & 63;
    const int m32  = lane & 31;
    const int h    = lane >> 5;
    const int chunk = blockIdx.x * 4 + (tid >> 6);   // 0..8191
    const s16x8* wf = (const s16x8*)w1f32;

    // ---- A fragments: 96 x-rows, fp32 global -> bf16 regs (once) ----
    // A[m=l&31][k=(l>>5)*8+j]; col = kt*16 + 8h + j
    s16x8 Af[3][4];
    {
        const float* xg = x + (size_t)chunk * (96 * N_IN);
        #pragma unroll
        for (int rt = 0; rt < 3; ++rt) {
            const float* rp = xg + (32 * rt + m32) * N_IN;
            #pragma unroll
            for (int kt = 0; kt < 3; ++kt) {
                const float* p = rp + 16 * kt + 8 * h;
                s16x8 f;
                #pragma unroll
                for (int q = 0; q < 4; ++q) {
                    const float2 u = *(const float2*)(p + 2 * q);
                    f[2 * q]     = f2bf(u.x);
                    f[2 * q + 1] = f2bf(u.y);
                }
                Af[rt][kt] = f;
            }
            s16x8 f3 = {0, 0, 0, 0, 0, 0, 0, 0};
            if (h == 0) {                       // cols 48,49 valid; rest pad
                const float2 u = *(const float2*)(rp + 48);
                f3[0] = f2bf(u.x); f3[1] = f2bf(u.y);
            }
            Af[rt][3] = f3;
        }
    }

    const int segbase = chunk * 4;

    // ---- ft-loop over 13 feature tiles (32 feats), B double-buffered ----
    s16x8 Bc[4], Bn[4];
    #pragma unroll
    for (int kt = 0; kt < 4; ++kt) Bc[kt] = wf[kt * 64 + lane];

    for (int ft = 0; ft < 13; ++ft) {
        const int ftn = (ft < 12) ? ft + 1 : 12;
        #pragma unroll
        for (int kt = 0; kt < 4; ++kt) Bn[kt] = wf[(ftn * 4 + kt) * 64 + lane];

        float s0 = 0.f, s1 = 0.f, s2 = 0.f, s3 = 0.f;
        #pragma unroll
        for (int rt = 0; rt < 3; ++rt) {
            f32x16 acc;
            #pragma unroll
            for (int r = 0; r < 16; ++r) acc[r] = 0.f;
            #pragma unroll
            for (int kt = 0; kt < 4; ++kt)
                acc = __builtin_amdgcn_mfma_f32_32x32x16_bf16(
                        __builtin_bit_cast(bfx8, Af[rt][kt]),
                        __builtin_bit_cast(bfx8, Bc[kt]), acc, 0, 0, 0);
            // C/D: row = (reg&3) + 8*(reg>>2) + 4h + 32rt; col = m32.
            // Segment boundary (24|48|72) falls between reg-groups:
            // rt=0: regs 0..11 -> seg0, 12..15 -> seg1
            // rt=1: regs 0..7  -> seg1, 8..15  -> seg2
            // rt=2: regs 0..3  -> seg2, 4..15  -> seg3   (uniform in h, m32)
            float c0 = 0.f, c1 = 0.f;
            #pragma unroll
            for (int r = 0; r < 16; ++r) {
                const float v = fmaxf(acc[r], 0.f);
                if ((r >> 2) < 3 - rt) c0 += v; else c1 += v;
            }
            if (rt == 0)      { s0 += c0; s1 += c1; }
            else if (rt == 1) { s1 += c0; s2 += c1; }
            else              { s2 += c0; s3 += c1; }
        }
        // combine the two half-waves (h=0/1 hold interleaved rows)
        s0 += __shfl_xor(s0, 32);
        s1 += __shfl_xor(s1, 32);
        s2 += __shfl_xor(s2, 32);
        s3 += __shfl_xor(s3, 32);
        if (lane < 32) {
            const size_t fo = 32 * ft + lane;
            pooled[(size_t)(segbase + 0) * POOLED_STRIDE + fo] = f2bf(s0);
            pooled[(size_t)(segbase + 1) * POOLED_STRIDE + fo] = f2bf(s1);
            pooled[(size_t)(segbase + 2) * POOLED_STRIDE + fo] = f2bf(s2);
            pooled[(size_t)(segbase + 3) * POOLED_STRIDE + fo] = f2bf(s3);
        }
        #pragma unroll
        for (int kt = 0; kt < 4; ++kt) Bc[kt] = Bn[kt];
    }
}

// ================= phase 2: pooled[32768x400] @ W2^T via MFMA ===============
// 512 blocks x 256 thr = 2048 waves x 16 segments.
__global__ __launch_bounds__(256) void phase2_kernel(
    const short* __restrict__ pooled, const short* __restrict__ w2f,
    float* __restrict__ out)
{
    const int tid  = threadIdx.x;
    const int lane = tid & 63;
    const int m16  = lane & 15;
    const int quad = lane >> 4;
    const int segbase = (blockIdx.x * 4 + (tid >> 6)) * 16;
    const s16x8* wf = (const s16x8*)w2f;
    const short* arow = pooled + (size_t)(segbase + m16) * POOLED_STRIDE;

    f32x4 acc = {0.f, 0.f, 0.f, 0.f};
    s16x8 zero = {0, 0, 0, 0, 0, 0, 0, 0};
    #pragma unroll
    for (int kt = 0; kt < 13; ++kt) {
        const s16x8 b = wf[kt * 64 + lane];
        const s16x8 a = (kt == 12 && quad >= 2)
                            ? zero
                            : *(const s16x8*)(arow + kt * 32 + quad * 8);
        acc = __builtin_amdgcn_mfma_f32_16x16x32_bf16(
                __builtin_bit_cast(bfx8, a), __builtin_bit_cast(bfx8, b),
                acc, 0, 0, 0);
    }
    // D: row(seg offset)=quad*4+reg, col(class)=m16
    if (m16 < C_OUT) {
        #pragma unroll
        for (int rg = 0; rg < 4; ++rg)
            out[(size_t)(segbase + quad * 4 + rg) * C_OUT + m16] =
                acc[rg] * (1.0f / 24.0f);
    }
}

// ================= fallback (round-3 fused kernel, verbatim) ================
#define FB_CPB 4
#define FB_NTHREADS 320
#define FB_XS_STRIDE 72
#define FB_XS_ROWS (FB_CPB * 48)

__global__ __launch_bounds__(FB_NTHREADS) void classifier_fb(
    const float* __restrict__ x, const short* __restrict__ w1f,
    const float* __restrict__ w2t, float* __restrict__ out)
{
    __shared__ short xs[FB_XS_ROWS * FB_XS_STRIDE];
    __shared__ float pooled[2 * K_FEAT];

    const int tid  = threadIdx.x;
    const int wave = tid >> 6;
    const int lane = tid & 63;
    const int m16  = lane & 15;
    const int quad = lane >> 4;

    {
        const float* xb = x + (size_t)blockIdx.x * (FB_XS_ROWS * N_IN);
        #pragma unroll
        for (int it = 0; it < (FB_XS_ROWS * 25) / FB_NTHREADS; ++it) {
            const int i = tid + it * FB_NTHREADS;
            const int r = i / 25;
            const int c2 = i - r * 25;
            const float2 v = *(const float2*)(xb + 2 * i);
            const int packed = (unsigned short)f2bf(v.x) |
                               ((unsigned)(unsigned short)f2bf(v.y) << 16);
            *(int*)&xs[r * FB_XS_STRIDE + 2 * c2] = packed;
        }
        for (int i = tid; i < FB_XS_ROWS * 7; i += FB_NTHREADS) {
            const int r = i / 7;
            const int c = 50 + 2 * (i - r * 7);
            *(int*)&xs[r * FB_XS_STRIDE + c] = 0;
        }
    }

    s16x8 bfrag[5][2];
    {
        const s16x8* wf = (const s16x8*)w1f;
        #pragma unroll
        for (int t = 0; t < 5; ++t)
            #pragma unroll
            for (int s = 0; s < 2; ++s)
                bfrag[t][s] = wf[((wave * 5 + t) * 2 + s) * 64 + lane];
    }

    const int o    = tid >> 4;
    const int part = tid & 15;
    const int segO = (o >= 10) ? 1 : 0;
    const int cls  = o - segO * 10;
    float w2r[25];
    #pragma unroll
    for (int j = 0; j < 25; ++j) w2r[j] = w2t[j * FB_NTHREADS + tid];

    __syncthreads();

    for (int ciq = 0; ciq < FB_CPB; ++ciq) {
        s16x8 a[3][2];
        #pragma unroll
        for (int r = 0; r < 3; ++r) {
            const short* arow =
                &xs[(ciq * 48 + r * 16 + m16) * FB_XS_STRIDE + quad * 8];
            a[r][0] = *(const s16x8*)(arow);
            a[r][1] = *(const s16x8*)(arow + 32);
        }
        #pragma unroll
        for (int t = 0; t < 5; ++t) {
            float c0 = 0.f, c1 = 0.f;
            #pragma unroll
            for (int r = 0; r < 3; ++r) {
                f32x4 acc = {0.f, 0.f, 0.f, 0.f};
                acc = __builtin_amdgcn_mfma_f32_16x16x32_bf16(
                        __builtin_bit_cast(bfx8, a[r][0]),
                        __builtin_bit_cast(bfx8, bfrag[t][0]), acc, 0, 0, 0);
                acc = __builtin_amdgcn_mfma_f32_16x16x32_bf16(
                        __builtin_bit_cast(bfx8, a[r][1]),
                        __builtin_bit_cast(bfx8, bfrag[t][1]), acc, 0, 0, 0);
                const float s = fmaxf(acc[0], 0.f) + fmaxf(acc[1], 0.f)
                              + fmaxf(acc[2], 0.f) + fmaxf(acc[3], 0.f);
                if (r * 4 + quad < 6) c0 += s; else c1 += s;
            }
            c0 += __shfl_xor(c0, 16); c0 += __shfl_xor(c0, 32);
            c1 += __shfl_xor(c1, 16); c1 += __shfl_xor(c1, 32);
            if (quad == 0) {
                const int feat = (wave * 5 + t) * 16 + m16;
                pooled[feat] = c0;
                pooled[K_FEAT + feat] = c1;
            }
        }
        __syncthreads();

        float sum = 0.f;
        const float* pv = &pooled[segO * K_FEAT + part * 25];
        #pragma unroll
        for (int j = 0; j < 25; ++j) sum += pv[j] * w2r[j];
        sum += __shfl_down(sum, 8, 16);
        sum += __shfl_down(sum, 4, 16);
        sum += __shfl_down(sum, 2, 16);
        sum += __shfl_down(sum, 1, 16);
        if (part == 0) {
            const int chunk = blockIdx.x * FB_CPB + ciq;
            out[(chunk * 2 + segO) * C_OUT + cls] = sum * (1.0f / 24.0f);
        }
        __syncthreads();
    }
}

// ============================== launch ======================================
extern "C" void kernel_launch(void* const* d_in, const int* in_sizes, int n_in,
                              void* d_out, int out_size, void* d_ws, size_t ws_size,
                              hipStream_t stream) {
    const float* x  = (const float*)d_in[0];
    const float* W1 = (const float*)d_in[1];
    const float* W2 = (const float*)d_in[2];
    float* out = (float*)d_out;

    short* w1f   = (short*)d_ws;
    float* w2t   = (float*)((char*)d_ws + W2T_OFF_BYTES);
    short* w2f   = (short*)((char*)d_ws + W2F_OFF_BYTES);
    short* w1f32 = (short*)((char*)d_ws + W1F32_OFF_BYTES);
    short* pooled = (short*)((char*)d_ws + POOLED_OFF_BYTES);

    prep_kernel<<<(PREP_TASKS + 255) / 256, 256, 0, stream>>>(W1, W2, w1f, w2t,
                                                              w2f, w1f32);

    if (ws_size >= WS_NEEDED) {
        phase1_kernel<<<2048, 256, 0, stream>>>(x, w1f32, pooled);
        phase2_kernel<<<512, 256, 0, stream>>>(pooled, w2f, out);
    } else {
        classifier_fb<<<4096, FB_NTHREADS, 0, stream>>>(x, w1f, w2t, out);
    }
}